// Round 5
// baseline (101.104 us; speedup 1.0000x reference)
//
#include <hip/hip_runtime.h>
#include <hip/hip_bf16.h>

// Problem constants (fixed by reference).
#define BN 65536   // batch
#define FD 128     // feature dim (K of layer 1)
#define HD 256     // hidden dim (N of layer 1)
#define DN 8       // domains
#define NB 256     // binning blocks (BN / 256)
#define TM 64      // rows (samples) per main-kernel tile
#define SLOTS 8192 // worst-case (k,d) tile slots: 1024 tiles * 8 domains
#define GRID_MAIN 1024

typedef float f32x4 __attribute__((ext_vector_type(4)));
using bf16x8 = __attribute__((ext_vector_type(8))) __bf16;
typedef unsigned short us4 __attribute__((ext_vector_type(4)));

__device__ __forceinline__ unsigned short f2bf(float f) {
  unsigned int x = __float_as_uint(f);
  x += 0x7fffu + ((x >> 16) & 1u);   // round-to-nearest-even
  return (unsigned short)(x >> 16);
}

// ---- k_pre: single-pass fused prep.
// Blocks 0..255: domain binning via per-wave ballot histograms (no LDS atomic
// chains) + ONE global atomicAdd per (block,domain) to reserve a packed range
// in perm[d<<16 ...], then direct scatter. Within-domain order is atomic-
// nondeterministic, which is fine: each row's output value is an independent
// per-row dot product, so any packing is bitwise-correct (proven in R2).
// Blocks 256..287: W1 [d][f][h] f32 -> W1T [d][h][f] bf16 LDS-tile transpose.
__global__ __launch_bounds__(256) void k_pre(
    const float* __restrict__ W1, const int* __restrict__ ids,
    unsigned short* __restrict__ W1T, int* __restrict__ g_cnt,
    int* __restrict__ perm) {
  __shared__ unsigned short tile[64][136];
  __shared__ int wcnt[4][DN];   // per-wave domain counts -> exclusive wave offsets
  __shared__ int base[DN];      // block's global base per domain
  int t = threadIdx.x, bid = blockIdx.x;

  if (bid < NB) {
    int w = t >> 6, l = t & 63;
    int i = bid * 256 + t;
    int id = ids[i];
    unsigned long long my_mask = 0;
    int cnt_l = 0;
#pragma unroll
    for (int d = 0; d < DN; d++) {
      unsigned long long bm = __ballot(id == d);
      if (id == d) my_mask = bm;
      if (l == d) cnt_l = __popcll(bm);
    }
    if (l < DN) wcnt[w][l] = cnt_l;
    int rank = __popcll(my_mask & ((1ull << l) - 1ull));
    __syncthreads();
    if (t < DN) {
      int s0 = wcnt[0][t], s1 = wcnt[1][t], s2 = wcnt[2][t], s3 = wcnt[3][t];
      wcnt[0][t] = 0; wcnt[1][t] = s0; wcnt[2][t] = s0 + s1;
      wcnt[3][t] = s0 + s1 + s2;
      base[t] = atomicAdd(&g_cnt[t], s0 + s1 + s2 + s3);
    }
    __syncthreads();
    perm[(id << 16) + base[id] + wcnt[w][id] + rank] = i;
  } else {
    int db = (bid - NB) >> 2, hb = (bid - NB) & 3;   // domain, h-quarter
    int fr = t >> 4, hq = t & 15;
    const float* src = W1 + (size_t)db * FD * HD + hb * 64 + hq * 4;
#pragma unroll
    for (int jj = 0; jj < 8; jj++) {
      int f = fr + 16 * jj;
      f32x4 v = *(const f32x4*)(src + (size_t)f * HD);
#pragma unroll
      for (int e = 0; e < 4; e++) tile[hq * 4 + e][f] = f2bf(v[e]);
    }
    __syncthreads();
    unsigned short* dst = W1T + (size_t)db * HD * FD + (size_t)hb * 64 * FD;
    int h = t >> 2, c = t & 3;
#pragma unroll
    for (int j = 0; j < 4; j++) {
      int f = c * 32 + j * 8;
      *(us4*)(dst + h * FD + f)     = *(const us4*)&tile[h][f];
      *(us4*)(dst + h * FD + f + 4) = *(const us4*)&tile[h][f + 4];
    }
  }
}

// ---- kmain: self-scheduled over the (k,d) slot space using only g_cnt.
// Slot s -> d = s&7, k = s>>3; active iff k*TM < g_cnt[d]. Per tile
// (domain d, 64 rows): h = relu(x W1 + b1); out = h.W2 + b2.
// 8 waves; wave w owns cols [w*32,w*32+32) x all 64 rows -> acc[4][2].
// B fragments + epilogue params hoisted before the staging barrier (ILP).
// A: row=lane&15, k=8*(lane>>4)+e. B: col=lane&15, same k. C/D: col=lane&15,
// row=(lane>>4)*4+q  (layouts verified rounds 1-4).
__global__ __launch_bounds__(512, 4) void kmain(
    const float* __restrict__ x, const float* __restrict__ b1,
    const float* __restrict__ W2, const float* __restrict__ b2,
    const unsigned short* __restrict__ W1T, const int* __restrict__ perm,
    const int* __restrict__ g_cnt, float* __restrict__ out) {
  __shared__ unsigned short xs[TM * FD];     // 16 KB swizzled bf16 x-tile
  __shared__ float s_red[TM][9];             // padded row-sum staging
  int t = threadIdx.x;
  int lane = t & 63, w = t >> 6;
  int lg = lane >> 4, lr = lane & 15;

  for (int s = blockIdx.x; s < SLOTS; s += GRID_MAIN) {
    int d = s & 7, k = s >> 3;
    int rows = g_cnt[d] - k * TM;            // block-uniform
    if (rows <= 0) continue;
    rows = min(rows, TM);
    const int* pr = perm + (d << 16) + k * TM;
    const unsigned short* Wd = W1T + (size_t)d * HD * FD;

    // ---- hoisted loads: B fragments + epilogue params (independent of LDS).
    float b1v[2], w2v[2];
    bf16x8 bfr[4][2];
#pragma unroll
    for (int nt = 0; nt < 2; nt++) {
      int col = w * 32 + nt * 16 + lr;
      b1v[nt] = b1[d * HD + col];
      w2v[nt] = W2[d * HD + col];
#pragma unroll
      for (int ks = 0; ks < 4; ks++)
        bfr[ks][nt] = *(const bf16x8*)(Wd + (size_t)col * FD + ks * 32 + lg * 8);
    }

    // ---- stage x rows -> bf16 LDS (swizzled: us ^= (row&7)<<3).
    {
      int r = t >> 3, c8 = t & 7;
      int gi = pr[min(r, rows - 1)];
      const float* xr = x + (size_t)gi * FD;
      f32x4 v[4];
#pragma unroll
      for (int j = 0; j < 4; j++) v[j] = *(const f32x4*)(xr + (c8 + 8 * j) * 4);
#pragma unroll
      for (int j = 0; j < 4; j++) {
        int fc = c8 + 8 * j;
        int us = (r * FD + fc * 4) ^ ((r & 7) << 3);
        us4 wv;
        wv[0] = f2bf(v[j][0]); wv[1] = f2bf(v[j][1]);
        wv[2] = f2bf(v[j][2]); wv[3] = f2bf(v[j][3]);
        *(us4*)&xs[us] = wv;
      }
    }
    __syncthreads();

    f32x4 acc[4][2];
#pragma unroll
    for (int mf = 0; mf < 4; mf++)
#pragma unroll
      for (int nt = 0; nt < 2; nt++) acc[mf][nt] = (f32x4){0.f, 0.f, 0.f, 0.f};

#pragma unroll
    for (int ks = 0; ks < 4; ks++) {
      bf16x8 a[4];
#pragma unroll
      for (int mf = 0; mf < 4; mf++) {
        int row = mf * 16 + lr;
        int us = (row * FD + ks * 32 + lg * 8) ^ ((row & 7) << 3);
        a[mf] = *(const bf16x8*)&xs[us];
      }
#pragma unroll
      for (int nt = 0; nt < 2; nt++)
#pragma unroll
        for (int mf = 0; mf < 4; mf++)
          acc[mf][nt] = __builtin_amdgcn_mfma_f32_16x16x32_bf16(a[mf], bfr[ks][nt], acc[mf][nt], 0, 0, 0);
    }

    // ---- fused layer 2 (fp32): relu(acc + b1) . W2, 16-lane shfl reduce.
    float part[4][4];
#pragma unroll
    for (int mf = 0; mf < 4; mf++)
#pragma unroll
      for (int q = 0; q < 4; q++) part[mf][q] = 0.f;
#pragma unroll
    for (int nt = 0; nt < 2; nt++)
#pragma unroll
      for (int mf = 0; mf < 4; mf++)
#pragma unroll
        for (int q = 0; q < 4; q++) {
          float h = acc[mf][nt][q] + b1v[nt];
          h = h > 0.f ? h : 0.f;
          part[mf][q] = fmaf(h, w2v[nt], part[mf][q]);
        }
#pragma unroll
    for (int off = 1; off < 16; off <<= 1)
#pragma unroll
      for (int mf = 0; mf < 4; mf++)
#pragma unroll
        for (int q = 0; q < 4; q++)
          part[mf][q] += __shfl_xor(part[mf][q], off);
    if (lr == 0) {
#pragma unroll
      for (int mf = 0; mf < 4; mf++)
#pragma unroll
        for (int q = 0; q < 4; q++)
          s_red[mf * 16 + lg * 4 + q][w] = part[mf][q];
    }
    __syncthreads();
    if (t < rows) {
      const float* sr = s_red[t];
      out[pr[t]] = sr[0] + sr[1] + sr[2] + sr[3] + sr[4] + sr[5] + sr[6] + sr[7]
                   + b2[d];
    }
    __syncthreads();   // xs/s_red reused next grid-stride iteration
  }
}

extern "C" void kernel_launch(void* const* d_in, const int* in_sizes, int n_in,
                              void* d_out, int out_size, void* d_ws, size_t ws_size,
                              hipStream_t stream) {
  const float* x   = (const float*)d_in[0];
  const int*   ids = (const int*)d_in[1];
  const float* W1  = (const float*)d_in[2];
  const float* b1  = (const float*)d_in[3];
  const float* W2  = (const float*)d_in[4];
  const float* b2  = (const float*)d_in[5];
  float* out = (float*)d_out;

  // Workspace carve (ints). g_cnt zeroed by memset; everything else is
  // written before read (ws is poisoned each iteration).
  int* ws_i = (int*)d_ws;
  int* g_cnt = ws_i;                // 8 (own 64B line)
  int* perm  = ws_i + 4096;         // 8 * 65536  (2 MB, 16B-aligned)
  unsigned short* W1T = (unsigned short*)(ws_i + 4096 + DN * BN);  // 512 KB

  hipMemsetAsync(g_cnt, 0, DN * sizeof(int), stream);
  hipLaunchKernelGGL(k_pre, dim3(NB + 32), dim3(256), 0, stream,
                     W1, ids, W1T, g_cnt, perm);
  hipLaunchKernelGGL(kmain, dim3(GRID_MAIN), dim3(512), 0, stream, x, b1, W2, b2,
                     W1T, perm, g_cnt, out);
}